// Round 1
// baseline (1233.547 us; speedup 1.0000x reference)
//
#include <hip/hip_runtime.h>
#include <cstddef>

#define NN   30000
#define NE   240000
#define NT   (NN + NE)   /* edges incl. self-loops = 270000 */
#define D1   512
#define CH1  256
#define D2   128
#define CH2  64
#define NCLS 20

// ---------------------------------------------------------------- utilities
__global__ __launch_bounds__(256) void k_zero4(float4* p, int n4) {
  int i = blockIdx.x * 256 + threadIdx.x;
  if (i < n4) p[i] = make_float4(0.f, 0.f, 0.f, 0.f);
}

__global__ __launch_bounds__(256) void k_deg(const int* __restrict__ dst,
                                             const float* __restrict__ eattr,
                                             float* __restrict__ cnt,
                                             float* __restrict__ lsum) {
  int e = blockIdx.x * 256 + threadIdx.x;
  if (e < NE) {
    int d = dst[e];
    atomicAdd(&cnt[d], 1.0f);
    atomicAdd(&lsum[d], eattr[e]);
  }
}

__global__ __launch_bounds__(256) void k_loopattr(const float* __restrict__ cnt,
                                                  const float* __restrict__ lsum,
                                                  float* __restrict__ loop_attr) {
  int n = blockIdx.x * 256 + threadIdx.x;
  if (n < NN) loop_attr[n] = lsum[n] / fmaxf(cnt[n], 1.0f);
}

// ---------------------------------------------------------------- GEMM
// C[m,n] = sum_k A[m,k] * W[n,k] + bias[n]   (A: MxK, W: NxK row-major)
// 64x64 tile, BK=16, 256 threads, 4x4 per thread. Requires K % 16 == 0.
__global__ __launch_bounds__(256) void gemm_bias(const float* __restrict__ A,
                                                 const float* __restrict__ W,
                                                 const float* __restrict__ bias,
                                                 float* __restrict__ C,
                                                 int M, int N, int K) {
  __shared__ float As[16][68];
  __shared__ float Ws[16][68];
  const int bm = blockIdx.y * 64;
  const int bn = blockIdx.x * 64;
  const int tid = threadIdx.x;
  const int tx = tid & 15, ty = tid >> 4;
  const int lr = tid >> 2;        // 0..63 (tile row)
  const int lk = (tid & 3) * 4;   // 0,4,8,12 (k offset)
  float acc[4][4] = {};

  for (int k0 = 0; k0 < K; k0 += 16) {
    {
      int m = bm + lr;
      float4 v = (m < M) ? *(const float4*)(A + (size_t)m * K + k0 + lk)
                         : make_float4(0.f, 0.f, 0.f, 0.f);
      As[lk + 0][lr] = v.x; As[lk + 1][lr] = v.y;
      As[lk + 2][lr] = v.z; As[lk + 3][lr] = v.w;
    }
    {
      int n = bn + lr;
      float4 v = (n < N) ? *(const float4*)(W + (size_t)n * K + k0 + lk)
                         : make_float4(0.f, 0.f, 0.f, 0.f);
      Ws[lk + 0][lr] = v.x; Ws[lk + 1][lr] = v.y;
      Ws[lk + 2][lr] = v.z; Ws[lk + 3][lr] = v.w;
    }
    __syncthreads();
#pragma unroll
    for (int kk = 0; kk < 16; ++kk) {
      float a[4], b[4];
#pragma unroll
      for (int i = 0; i < 4; ++i) a[i] = As[kk][ty * 4 + i];
#pragma unroll
      for (int j = 0; j < 4; ++j) b[j] = Ws[kk][tx * 4 + j];
#pragma unroll
      for (int i = 0; i < 4; ++i)
#pragma unroll
        for (int j = 0; j < 4; ++j) acc[i][j] += a[i] * b[j];
    }
    __syncthreads();
  }

#pragma unroll
  for (int i = 0; i < 4; ++i) {
    int m = bm + ty * 4 + i;
    if (m >= M) continue;
#pragma unroll
    for (int j = 0; j < 4; ++j) {
      int n = bn + tx * 4 + j;
      if (n < N) C[(size_t)m * N + n] = acc[i][j] + (bias ? bias[n] : 0.f);
    }
  }
}

// ---------------------------------------------------------------- edge logits + exp + denom
// One wave per edge. Lanes [0,32) = head 0, [32,64) = head 1.
__global__ __launch_bounds__(256) void k_logits(const int* __restrict__ src,
                                                const int* __restrict__ dst,
                                                const float* __restrict__ eattr,
                                                const float* __restrict__ loop_attr,
                                                const float* __restrict__ xl,
                                                const float* __restrict__ xr,
                                                const float* __restrict__ We,
                                                const float* __restrict__ att,
                                                float* __restrict__ p,
                                                float* __restrict__ denom,
                                                int D, int ch) {
  int wid = blockIdx.x * 4 + (threadIdx.x >> 6);
  if (wid >= NT) return;
  int lane = threadIdx.x & 63;
  int h = lane >> 5, l = lane & 31;
  int s, d; float ea;
  if (wid < NE) { s = src[wid]; d = dst[wid]; ea = eattr[wid]; }
  else          { int n = wid - NE; s = n; d = n; ea = loop_attr[n]; }

  const float* xs = xl + (size_t)s * D + h * ch;
  const float* xd = xr + (size_t)d * D + h * ch;
  const float* we = We + h * ch;
  const float* at = att + h * ch;
  float acc = 0.f;
  for (int c = l; c < ch; c += 32) {
    float v = xs[c] + xd[c] + ea * we[c];
    v = (v > 0.f) ? v : 0.2f * v;
    acc += at[c] * v;
  }
#pragma unroll
  for (int off = 16; off > 0; off >>= 1) acc += __shfl_xor(acc, off);
  if (l == 0) {
    float pe = expf(acc);           // logits are O(1): no max-shift needed
    p[(size_t)wid * 2 + h] = pe;
    atomicAdd(&denom[(size_t)d * 2 + h], pe);
  }
}

// ---------------------------------------------------------------- weighted scatter-add
// One wave per edge; row-wise coalesced fp32 atomics.
__global__ __launch_bounds__(256) void k_scatter(const int* __restrict__ src,
                                                 const int* __restrict__ dst,
                                                 const float* __restrict__ p,
                                                 const float* __restrict__ denom,
                                                 const float* __restrict__ xl,
                                                 float* __restrict__ out,
                                                 int D, int ch) {
  int wid = blockIdx.x * 4 + (threadIdx.x >> 6);
  if (wid >= NT) return;
  int lane = threadIdx.x & 63;
  int s, d;
  if (wid < NE) { s = src[wid]; d = dst[wid]; }
  else          { s = d = wid - NE; }
  float a0 = p[(size_t)wid * 2 + 0] / denom[(size_t)d * 2 + 0];
  float a1 = p[(size_t)wid * 2 + 1] / denom[(size_t)d * 2 + 1];
  const float* xs = xl + (size_t)s * D;
  float* od = out + (size_t)d * D;
  for (int idx = lane; idx < D; idx += 64) {
    float a = (idx < ch) ? a0 : a1;
    atomicAdd(&od[idx], a * xs[idx]);
  }
}

// ---------------------------------------------------------------- epilogues
// layer1: v = silu(agg + bias); rmsnorm(v) * w    (D = 512, in-place)
__global__ __launch_bounds__(256) void k_post_silu_rms(float* __restrict__ h,
                                                       const float* __restrict__ bias,
                                                       const float* __restrict__ w) {
  int n = blockIdx.x;
  int t = threadIdx.x;
  float* row = h + (size_t)n * D1;
  float v0 = row[t] + bias[t];
  float v1 = row[t + 256] + bias[t + 256];
  v0 = v0 / (1.f + expf(-v0));
  v1 = v1 / (1.f + expf(-v1));
  float ss = v0 * v0 + v1 * v1;
#pragma unroll
  for (int off = 32; off > 0; off >>= 1) ss += __shfl_xor(ss, off);
  __shared__ float red[4];
  if ((t & 63) == 0) red[t >> 6] = ss;
  __syncthreads();
  float tot = red[0] + red[1] + red[2] + red[3];
  float inv = rsqrtf(tot / (float)D1 + 1e-5f);
  row[t] = v0 * inv * w[t];
  row[t + 256] = v1 * inv * w[t + 256];
}

// layer2: v = agg + bias; rmsnorm(v) * w   (D = 128, one wave per node, in-place)
__global__ __launch_bounds__(256) void k_post_rms128(float* __restrict__ h,
                                                     const float* __restrict__ bias,
                                                     const float* __restrict__ w) {
  int wid = blockIdx.x * 4 + (threadIdx.x >> 6);
  if (wid >= NN) return;
  int lane = threadIdx.x & 63;
  float* row = h + (size_t)wid * D2;
  float v0 = row[lane] + bias[lane];
  float v1 = row[lane + 64] + bias[lane + 64];
  float ss = v0 * v0 + v1 * v1;
#pragma unroll
  for (int off = 32; off > 0; off >>= 1) ss += __shfl_xor(ss, off);
  float inv = rsqrtf(ss / (float)D2 + 1e-5f);
  row[lane] = v0 * inv * w[lane];
  row[lane + 64] = v1 * inv * w[lane + 64];
}

// ---------------------------------------------------------------- launch
extern "C" void kernel_launch(void* const* d_in, const int* in_sizes, int n_in,
                              void* d_out, int out_size, void* d_ws, size_t ws_size,
                              hipStream_t stream) {
  const float* x     = (const float*)d_in[0];
  const int*   ei    = (const int*)  d_in[1];
  const float* eattr = (const float*)d_in[2];
  const float* Wl1   = (const float*)d_in[3];
  const float* bl1   = (const float*)d_in[4];
  const float* Wr1   = (const float*)d_in[5];
  const float* br1   = (const float*)d_in[6];
  const float* We1   = (const float*)d_in[7];
  const float* att1  = (const float*)d_in[8];
  const float* bias1 = (const float*)d_in[9];
  const float* Wl2   = (const float*)d_in[10];
  const float* bl2   = (const float*)d_in[11];
  const float* Wr2   = (const float*)d_in[12];
  const float* br2   = (const float*)d_in[13];
  const float* We2   = (const float*)d_in[14];
  const float* att2  = (const float*)d_in[15];
  const float* bias2 = (const float*)d_in[16];
  const float* w_ln1 = (const float*)d_in[17];
  const float* w_ln3 = (const float*)d_in[18];
  const float* W_out = (const float*)d_in[19];
  float* out = (float*)d_out;
  (void)in_sizes; (void)n_in; (void)out_size; (void)ws_size;

  const int* src = ei;
  const int* dst = ei + NE;

  // workspace carve-up (256B aligned)
  char* wsp = (char*)d_ws;
  auto alloc = [&](size_t nfloats) {
    float* ptr = (float*)wsp;
    wsp += ((nfloats * sizeof(float) + 255) / 256) * 256;
    return ptr;
  };
  float* cnt       = alloc(NN);
  float* lsum      = alloc(NN);
  float* loop_attr = alloc(NN);
  float* denom1    = alloc((size_t)NN * 2);
  float* denom2    = alloc((size_t)NN * 2);
  float* p1        = alloc((size_t)NT * 2);
  float* p2        = alloc((size_t)NT * 2);
  float* xl1       = alloc((size_t)NN * D1);
  float* xr1       = alloc((size_t)NN * D1);   // reused as agg1/h1 after logits1
  float* xl2       = alloc((size_t)NN * D2);
  float* xr2       = alloc((size_t)NN * D2);   // reused as agg2/h2 after logits2

  auto Z4 = [&](float* ptr, size_t n) {
    int n4 = (int)(n / 4);
    k_zero4<<<(n4 + 255) / 256, 256, 0, stream>>>((float4*)ptr, n4);
  };

  const int EB = (NT + 3) / 4;   // one wave per edge, 4 waves/block

  // --- degree + self-loop attr ---
  Z4(cnt, NN); Z4(lsum, NN); Z4(denom1, (size_t)NN * 2); Z4(denom2, (size_t)NN * 2);
  k_deg<<<(NE + 255) / 256, 256, 0, stream>>>(dst, eattr, cnt, lsum);
  k_loopattr<<<(NN + 255) / 256, 256, 0, stream>>>(cnt, lsum, loop_attr);

  // --- layer 1 ---
  gemm_bias<<<dim3(D1 / 64, (NN + 63) / 64), 256, 0, stream>>>(x, Wl1, bl1, xl1, NN, D1, 128);
  gemm_bias<<<dim3(D1 / 64, (NN + 63) / 64), 256, 0, stream>>>(x, Wr1, br1, xr1, NN, D1, 128);
  k_logits<<<EB, 256, 0, stream>>>(src, dst, eattr, loop_attr, xl1, xr1, We1, att1, p1, denom1, D1, CH1);
  float* agg1 = xr1;
  Z4(agg1, (size_t)NN * D1);
  k_scatter<<<EB, 256, 0, stream>>>(src, dst, p1, denom1, xl1, agg1, D1, CH1);
  k_post_silu_rms<<<NN, 256, 0, stream>>>(agg1, bias1, w_ln1);   // agg1 -> h1

  // --- layer 2 ---
  gemm_bias<<<dim3(D2 / 64, (NN + 63) / 64), 256, 0, stream>>>(agg1, Wl2, bl2, xl2, NN, D2, D1);
  gemm_bias<<<dim3(D2 / 64, (NN + 63) / 64), 256, 0, stream>>>(agg1, Wr2, br2, xr2, NN, D2, D1);
  k_logits<<<EB, 256, 0, stream>>>(src, dst, eattr, loop_attr, xl2, xr2, We2, att2, p2, denom2, D2, CH2);
  float* agg2 = xr2;
  Z4(agg2, (size_t)NN * D2);
  k_scatter<<<EB, 256, 0, stream>>>(src, dst, p2, denom2, xl2, agg2, D2, CH2);
  k_post_rms128<<<(NN + 3) / 4, 256, 0, stream>>>(agg2, bias2, w_ln3);  // agg2 -> h2

  // --- classifier head ---
  gemm_bias<<<dim3(1, (NN + 63) / 64), 256, 0, stream>>>(agg2, W_out, nullptr, out, NN, NCLS, D2);
}

// Round 2
// 584.870 us; speedup vs baseline: 2.1091x; 2.1091x over previous
//
#include <hip/hip_runtime.h>
#include <cstddef>

#define NN   30000
#define NE   240000
#define D1   512
#define D2   128
#define NCLS 20
#define NB   ((NN + 255) / 256)   /* 118 scan blocks */

// ---------------------------------------------------------------- utilities
__global__ __launch_bounds__(256) void k_zero(int* __restrict__ p, int n) {
  int i = blockIdx.x * 256 + threadIdx.x;
  if (i < n) p[i] = 0;
}

__global__ __launch_bounds__(256) void k_deg(const int* __restrict__ dst,
                                             const float* __restrict__ eattr,
                                             int* __restrict__ cnti,
                                             float* __restrict__ lsum) {
  int e = blockIdx.x * 256 + threadIdx.x;
  if (e < NE) {
    int d = dst[e];
    atomicAdd(&cnti[d], 1);
    atomicAdd(&lsum[d], eattr[e]);
  }
}

__global__ __launch_bounds__(256) void k_loopattr(const int* __restrict__ cnti,
                                                  const float* __restrict__ lsum,
                                                  float* __restrict__ la) {
  int n = blockIdx.x * 256 + threadIdx.x;
  if (n < NN) la[n] = lsum[n] / fmaxf((float)cnti[n], 1.0f);
}

// exclusive scan of cnti within each 256-block; block totals to bsum
__global__ __launch_bounds__(256) void k_scan1(const int* __restrict__ cnti,
                                               int* __restrict__ rowoff,
                                               int* __restrict__ bsum) {
  int i = blockIdx.x * 256 + threadIdx.x;
  int c = (i < NN) ? cnti[i] : 0;
  int lane = threadIdx.x & 63, w = threadIdx.x >> 6;
  int v = c;
#pragma unroll
  for (int o = 1; o < 64; o <<= 1) { int t = __shfl_up(v, o); if (lane >= o) v += t; }
  __shared__ int ws[4];
  if (lane == 63) ws[w] = v;
  __syncthreads();
  int add = 0;
  for (int k = 0; k < w; k++) add += ws[k];
  v += add;
  if (i < NN) rowoff[i] = v - c;          // exclusive within block
  if (threadIdx.x == 255) bsum[blockIdx.x] = v;
}

// exclusive scan of the NB block sums (single block, Hillis-Steele in LDS)
__global__ __launch_bounds__(128) void k_scan2(const int* __restrict__ bsum,
                                               int* __restrict__ boff) {
  __shared__ int s[128];
  int t = threadIdx.x;
  int orig = (t < NB) ? bsum[t] : 0;
  s[t] = orig;
  __syncthreads();
  for (int o = 1; o < 128; o <<= 1) {
    int v = (t >= o) ? s[t - o] : 0;
    __syncthreads();
    s[t] += v;
    __syncthreads();
  }
  boff[t] = s[t] - orig;
}

// counting-sort fill: edges grouped by destination
__global__ __launch_bounds__(256) void k_fill(const int* __restrict__ src,
                                              const int* __restrict__ dst,
                                              const float* __restrict__ eattr,
                                              const int* __restrict__ rowoff,
                                              const int* __restrict__ boff,
                                              int* __restrict__ cursor,
                                              int* __restrict__ ssrc,
                                              float* __restrict__ sattr) {
  int e = blockIdx.x * 256 + threadIdx.x;
  if (e < NE) {
    int d = dst[e];
    int pos = rowoff[d] + boff[d >> 8] + atomicAdd(&cursor[d], 1);
    ssrc[pos] = src[e];
    sattr[pos] = eattr[e];
  }
}

// ---------------------------------------------------------------- GEMM (fp32, vector ALU)
// C[m,n] = sum_k A[m,k]*W[n,k] + bias[n]   (A: MxK, W: NxK row-major), K%16==0
__global__ __launch_bounds__(256) void gemm_bias(const float* __restrict__ A,
                                                 const float* __restrict__ W,
                                                 const float* __restrict__ bias,
                                                 float* __restrict__ C,
                                                 int M, int N, int K) {
  __shared__ float As[16][68];
  __shared__ float Ws[16][68];
  const int bm = blockIdx.y * 64;
  const int bn = blockIdx.x * 64;
  const int tid = threadIdx.x;
  const int tx = tid & 15, ty = tid >> 4;
  const int lr = tid >> 2;
  const int lk = (tid & 3) * 4;
  float acc[4][4] = {};

  for (int k0 = 0; k0 < K; k0 += 16) {
    {
      int m = bm + lr;
      float4 v = (m < M) ? *(const float4*)(A + (size_t)m * K + k0 + lk)
                         : make_float4(0.f, 0.f, 0.f, 0.f);
      As[lk + 0][lr] = v.x; As[lk + 1][lr] = v.y;
      As[lk + 2][lr] = v.z; As[lk + 3][lr] = v.w;
    }
    {
      int n = bn + lr;
      float4 v = (n < N) ? *(const float4*)(W + (size_t)n * K + k0 + lk)
                         : make_float4(0.f, 0.f, 0.f, 0.f);
      Ws[lk + 0][lr] = v.x; Ws[lk + 1][lr] = v.y;
      Ws[lk + 2][lr] = v.z; Ws[lk + 3][lr] = v.w;
    }
    __syncthreads();
#pragma unroll
    for (int kk = 0; kk < 16; ++kk) {
      float a[4], b[4];
#pragma unroll
      for (int i = 0; i < 4; ++i) a[i] = As[kk][ty * 4 + i];
#pragma unroll
      for (int j = 0; j < 4; ++j) b[j] = Ws[kk][tx * 4 + j];
#pragma unroll
      for (int i = 0; i < 4; ++i)
#pragma unroll
        for (int j = 0; j < 4; ++j) acc[i][j] += a[i] * b[j];
    }
    __syncthreads();
  }

#pragma unroll
  for (int i = 0; i < 4; ++i) {
    int m = bm + ty * 4 + i;
    if (m >= M) continue;
#pragma unroll
    for (int j = 0; j < 4; ++j) {
      int n = bn + tx * 4 + j;
      if (n < N) C[(size_t)m * N + n] = acc[i][j] + (bias ? bias[n] : 0.f);
    }
  }
}

// ---------------------------------------------------------------- fused GATv2 aggregate
// One wave per destination node. Lane l owns channels [l*VEC, l*VEC+VEC).
// Head = lane>>5 (channel block boundary at D/2). Per edge: logit (leaky+att dot,
// half-wave reduce), exp, denom accumulate, weighted message accumulate — all in
// registers. Epilogue: alpha-normalize + bias (+SiLU) + RMSNorm*w, streamed out.
template <int D, bool DO_SILU>
__global__ __launch_bounds__(256) void k_gat_fused(
    const int* __restrict__ ssrc, const float* __restrict__ sattr,
    const int* __restrict__ rowoff, const int* __restrict__ boff,
    const int* __restrict__ cnti, const float* __restrict__ la,
    const float* __restrict__ xl, const float* __restrict__ xr,
    const float* __restrict__ We, const float* __restrict__ att,
    const float* __restrict__ bias, const float* __restrict__ w_ln,
    float* __restrict__ out) {
  constexpr int VEC = D / 64;
  int n = blockIdx.x * 4 + (threadIdx.x >> 6);
  if (n >= NN) return;
  int lane = threadIdx.x & 63;
  int c0 = lane * VEC;

  float xd[VEC], we[VEC], at[VEC], acc[VEC] = {};
  float denom = 0.f;
#pragma unroll
  for (int k = 0; k < VEC; k++) {
    xd[k] = xr[(size_t)n * D + c0 + k];
    we[k] = We[c0 + k];
    at[k] = att[c0 + k];
  }

  int start = rowoff[n] + boff[n >> 8];
  int deg = cnti[n];
  for (int i = 0; i <= deg; i++) {          // last iteration = self-loop
    int s; float ea;
    if (i < deg) { s = ssrc[start + i]; ea = sattr[start + i]; }
    else         { s = n;               ea = la[n]; }
    const float* xsp = xl + (size_t)s * D + c0;
    float xs[VEC];
#pragma unroll
    for (int k = 0; k < VEC; k++) xs[k] = xsp[k];
    float part = 0.f;
#pragma unroll
    for (int k = 0; k < VEC; k++) {
      float v = xs[k] + xd[k] + ea * we[k];
      v = (v > 0.f) ? v : 0.2f * v;
      part += at[k] * v;
    }
#pragma unroll
    for (int o = 16; o > 0; o >>= 1) part += __shfl_xor(part, o);  // per-head (half-wave)
    float pe = __expf(part);
    denom += pe;
#pragma unroll
    for (int k = 0; k < VEC; k++) acc[k] += pe * xs[k];
  }

  float inv = 1.f / denom;                  // identical across each half-wave
  float vv[VEC], ss = 0.f;
#pragma unroll
  for (int k = 0; k < VEC; k++) {
    float v = acc[k] * inv + bias[c0 + k];
    if (DO_SILU) v = v / (1.f + __expf(-v));
    vv[k] = v;
    ss += v * v;
  }
#pragma unroll
  for (int o = 32; o > 0; o >>= 1) ss += __shfl_xor(ss, o);        // full-wave
  float rinv = rsqrtf(ss / (float)D + 1e-5f);
#pragma unroll
  for (int k = 0; k < VEC; k++)
    out[(size_t)n * D + c0 + k] = vv[k] * rinv * w_ln[c0 + k];
}

// ---------------------------------------------------------------- launch
extern "C" void kernel_launch(void* const* d_in, const int* in_sizes, int n_in,
                              void* d_out, int out_size, void* d_ws, size_t ws_size,
                              hipStream_t stream) {
  const float* x     = (const float*)d_in[0];
  const int*   ei    = (const int*)  d_in[1];
  const float* eattr = (const float*)d_in[2];
  const float* Wl1   = (const float*)d_in[3];
  const float* bl1   = (const float*)d_in[4];
  const float* Wr1   = (const float*)d_in[5];
  const float* br1   = (const float*)d_in[6];
  const float* We1   = (const float*)d_in[7];
  const float* att1  = (const float*)d_in[8];
  const float* bias1 = (const float*)d_in[9];
  const float* Wl2   = (const float*)d_in[10];
  const float* bl2   = (const float*)d_in[11];
  const float* Wr2   = (const float*)d_in[12];
  const float* br2   = (const float*)d_in[13];
  const float* We2   = (const float*)d_in[14];
  const float* att2  = (const float*)d_in[15];
  const float* bias2 = (const float*)d_in[16];
  const float* w_ln1 = (const float*)d_in[17];
  const float* w_ln3 = (const float*)d_in[18];
  const float* W_out = (const float*)d_in[19];
  float* out = (float*)d_out;
  (void)in_sizes; (void)n_in; (void)out_size; (void)ws_size;

  const int* src = ei;
  const int* dst = ei + NE;

  // workspace carve-up (256B aligned)
  char* wsp = (char*)d_ws;
  auto alloc = [&](size_t nbytes) {
    char* ptr = wsp;
    wsp += ((nbytes + 255) / 256) * 256;
    return ptr;
  };
  int*   cnti   = (int*)  alloc((size_t)NN * 4);     // }
  int*   cursor = (int*)  alloc((size_t)NN * 4);     // } contiguous: zeroed together
  float* lsum   = (float*)alloc((size_t)NN * 4);     // }
  float* la     = (float*)alloc((size_t)NN * 4);
  int*   rowoff = (int*)  alloc((size_t)NN * 4);
  int*   bsum   = (int*)  alloc(128 * 4);
  int*   boff   = (int*)  alloc(128 * 4);
  int*   ssrc   = (int*)  alloc((size_t)NE * 4);
  float* sattr  = (float*)alloc((size_t)NE * 4);
  float* xl1    = (float*)alloc((size_t)NN * D1 * 4);
  float* xr1    = (float*)alloc((size_t)NN * D1 * 4);
  float* h1     = (float*)alloc((size_t)NN * D1 * 4);
  float* xl2    = (float*)alloc((size_t)NN * D2 * 4);
  float* xr2    = (float*)alloc((size_t)NN * D2 * 4);
  float* h2     = (float*)alloc((size_t)NN * D2 * 4);

  // --- CSR build (counting sort by dst) + self-loop attrs ---
  k_zero<<<(3 * NN + 255) / 256, 256, 0, stream>>>(cnti, 3 * NN);  // cnti,cursor,lsum
  k_deg<<<(NE + 255) / 256, 256, 0, stream>>>(dst, eattr, cnti, lsum);
  k_loopattr<<<(NN + 255) / 256, 256, 0, stream>>>(cnti, lsum, la);
  k_scan1<<<NB, 256, 0, stream>>>(cnti, rowoff, bsum);
  k_scan2<<<1, 128, 0, stream>>>(bsum, boff);
  k_fill<<<(NE + 255) / 256, 256, 0, stream>>>(src, dst, eattr, rowoff, boff,
                                               cursor, ssrc, sattr);

  const int GB = (NN + 3) / 4;   // fused kernels: 1 wave/node, 4 waves/block

  // --- layer 1 ---
  gemm_bias<<<dim3(D1 / 64, (NN + 63) / 64), 256, 0, stream>>>(x, Wl1, bl1, xl1, NN, D1, 128);
  gemm_bias<<<dim3(D1 / 64, (NN + 63) / 64), 256, 0, stream>>>(x, Wr1, br1, xr1, NN, D1, 128);
  k_gat_fused<D1, true><<<GB, 256, 0, stream>>>(ssrc, sattr, rowoff, boff, cnti, la,
                                                xl1, xr1, We1, att1, bias1, w_ln1, h1);

  // --- layer 2 ---
  gemm_bias<<<dim3(D2 / 64, (NN + 63) / 64), 256, 0, stream>>>(h1, Wl2, bl2, xl2, NN, D2, D1);
  gemm_bias<<<dim3(D2 / 64, (NN + 63) / 64), 256, 0, stream>>>(h1, Wr2, br2, xr2, NN, D2, D1);
  k_gat_fused<D2, false><<<GB, 256, 0, stream>>>(ssrc, sattr, rowoff, boff, cnti, la,
                                                 xl2, xr2, We2, att2, bias2, w_ln3, h2);

  // --- classifier head ---
  gemm_bias<<<dim3(1, (NN + 63) / 64), 256, 0, stream>>>(h2, W_out, nullptr, out, NN, NCLS, D2);
}

// Round 3
// 420.117 us; speedup vs baseline: 2.9362x; 1.3922x over previous
//
#include <hip/hip_runtime.h>
#include <cstddef>

#define NN   30000
#define NE   240000
#define D1   512
#define D2   128
#define NCLS 20
#define NB   ((NN + 255) / 256)   /* 118 scan blocks */

typedef __attribute__((ext_vector_type(8))) short short8;
typedef __attribute__((ext_vector_type(4))) float f32x4;

__device__ __forceinline__ unsigned short f2b(float f) {
  union { float f; unsigned int u; } c; c.f = f;
  unsigned int r = (c.u + 0x7fff + ((c.u >> 16) & 1)) >> 16;  // RNE
  return (unsigned short)r;
}

// ---------------------------------------------------------------- utilities
__global__ __launch_bounds__(256) void k_zero(int* __restrict__ p, int n) {
  int i = blockIdx.x * 256 + threadIdx.x;
  if (i < n) p[i] = 0;
}

// fp32 -> bf16 (n % 4 == 0)
__global__ __launch_bounds__(256) void k_f2b(const float* __restrict__ in,
                                             unsigned short* __restrict__ out, int n) {
  int i = (blockIdx.x * 256 + threadIdx.x) * 4;
  if (i < n) {
    float4 v = *(const float4*)(in + i);
    ushort4 o;
    o.x = f2b(v.x); o.y = f2b(v.y); o.z = f2b(v.z); o.w = f2b(v.w);
    *(ushort4*)(out + i) = o;
  }
}

__global__ __launch_bounds__(256) void k_deg(const int* __restrict__ dst,
                                             const float* __restrict__ eattr,
                                             int* __restrict__ cnti,
                                             float* __restrict__ lsum) {
  int e = blockIdx.x * 256 + threadIdx.x;
  if (e < NE) {
    int d = dst[e];
    atomicAdd(&cnti[d], 1);
    atomicAdd(&lsum[d], eattr[e]);
  }
}

__global__ __launch_bounds__(256) void k_loopattr(const int* __restrict__ cnti,
                                                  const float* __restrict__ lsum,
                                                  float* __restrict__ la) {
  int n = blockIdx.x * 256 + threadIdx.x;
  if (n < NN) la[n] = lsum[n] / fmaxf((float)cnti[n], 1.0f);
}

__global__ __launch_bounds__(256) void k_scan1(const int* __restrict__ cnti,
                                               int* __restrict__ rowoff,
                                               int* __restrict__ bsum) {
  int i = blockIdx.x * 256 + threadIdx.x;
  int c = (i < NN) ? cnti[i] : 0;
  int lane = threadIdx.x & 63, w = threadIdx.x >> 6;
  int v = c;
#pragma unroll
  for (int o = 1; o < 64; o <<= 1) { int t = __shfl_up(v, o); if (lane >= o) v += t; }
  __shared__ int ws[4];
  if (lane == 63) ws[w] = v;
  __syncthreads();
  int add = 0;
  for (int k = 0; k < w; k++) add += ws[k];
  v += add;
  if (i < NN) rowoff[i] = v - c;
  if (threadIdx.x == 255) bsum[blockIdx.x] = v;
}

__global__ __launch_bounds__(128) void k_scan2(const int* __restrict__ bsum,
                                               int* __restrict__ boff) {
  __shared__ int s[128];
  int t = threadIdx.x;
  int orig = (t < NB) ? bsum[t] : 0;
  s[t] = orig;
  __syncthreads();
  for (int o = 1; o < 128; o <<= 1) {
    int v = (t >= o) ? s[t - o] : 0;
    __syncthreads();
    s[t] += v;
    __syncthreads();
  }
  boff[t] = s[t] - orig;
}

__global__ __launch_bounds__(256) void k_fill(const int* __restrict__ src,
                                              const int* __restrict__ dst,
                                              const float* __restrict__ eattr,
                                              const int* __restrict__ rowoff,
                                              const int* __restrict__ boff,
                                              int* __restrict__ cursor,
                                              int* __restrict__ ssrc,
                                              float* __restrict__ sattr) {
  int e = blockIdx.x * 256 + threadIdx.x;
  if (e < NE) {
    int d = dst[e];
    int pos = rowoff[d] + boff[d >> 8] + atomicAdd(&cursor[d], 1);
    ssrc[pos] = src[e];
    sattr[pos] = eattr[e];
  }
}

// ---------------------------------------------------------------- bf16 MFMA GEMM
// C[m,n] = sum_k A[m,k]*W[n,k] + bias[n].  A: MxK bf16, W: NxK bf16 (both
// K-contiguous = exactly the MFMA A/B operand order). 16x16x32 bf16 MFMA.
// BM=128, BN template (128 or 64), BK=32; 256 threads = 4 waves in 2x2.
// LDS K-stride padded +8 bf16 so frag ds_read_b128 is ~2-way (free).
template <int BN, int NT>   // NT = BN/32 tiles per wave in n
__global__ __launch_bounds__(256) void gemm_mfma(
    const unsigned short* __restrict__ A, const unsigned short* __restrict__ W,
    const float* __restrict__ bias, float* __restrict__ C,
    int M, int N, int K) {
  constexpr int BM = 128;
  constexpr int BK = 32;
  constexpr int LDK = BK + 8;
  __shared__ __align__(16) unsigned short As[BM * LDK];
  __shared__ __align__(16) unsigned short Bs[BN * LDK];
  const int bm = blockIdx.y * BM;
  const int bn = blockIdx.x * BN;
  const int tid = threadIdx.x;
  const int wid = tid >> 6, lane = tid & 63;
  const int wm = (wid >> 1) * 64;
  const int wn = (wid & 1) * (NT * 16);
  const int l16 = lane & 15, lq = lane >> 4;
  const int r0 = tid >> 2;            // staging row 0..63
  const int ks = (tid & 3) * 8;       // staging k-offset

  f32x4 acc[4][NT];
#pragma unroll
  for (int i = 0; i < 4; ++i)
#pragma unroll
    for (int j = 0; j < NT; ++j) acc[i][j] = (f32x4){0.f, 0.f, 0.f, 0.f};

  for (int k0 = 0; k0 < K; k0 += BK) {
#pragma unroll
    for (int p = 0; p < BM / 64; ++p) {
      int r = r0 + p * 64;
      int gm = bm + r;
      uint4 v = {0u, 0u, 0u, 0u};
      if (gm < M) v = *(const uint4*)(A + (size_t)gm * K + k0 + ks);
      *(uint4*)&As[r * LDK + ks] = v;
    }
#pragma unroll
    for (int p = 0; p < BN / 64; ++p) {
      int r = r0 + p * 64;
      int gn = bn + r;
      uint4 v = {0u, 0u, 0u, 0u};
      if (gn < N) v = *(const uint4*)(W + (size_t)gn * K + k0 + ks);
      *(uint4*)&Bs[r * LDK + ks] = v;
    }
    __syncthreads();
    short8 af[4], bfr[NT];
#pragma unroll
    for (int mt = 0; mt < 4; ++mt)
      af[mt] = *(const short8*)&As[(wm + mt * 16 + l16) * LDK + lq * 8];
#pragma unroll
    for (int nt = 0; nt < NT; ++nt)
      bfr[nt] = *(const short8*)&Bs[(wn + nt * 16 + l16) * LDK + lq * 8];
#pragma unroll
    for (int mt = 0; mt < 4; ++mt)
#pragma unroll
      for (int nt = 0; nt < NT; ++nt)
        acc[mt][nt] = __builtin_amdgcn_mfma_f32_16x16x32_bf16(
            af[mt], bfr[nt], acc[mt][nt], 0, 0, 0);
    __syncthreads();
  }

#pragma unroll
  for (int mt = 0; mt < 4; ++mt)
#pragma unroll
    for (int nt = 0; nt < NT; ++nt)
#pragma unroll
      for (int r = 0; r < 4; ++r) {
        int row = bm + wm + mt * 16 + lq * 4 + r;
        int col = bn + wn + nt * 16 + l16;
        if (row < M)
          C[(size_t)row * N + col] = acc[mt][nt][r] + (bias ? bias[col] : 0.f);
      }
}

// ---------------------------------------------------------------- fp32 GEMM (head only)
__global__ __launch_bounds__(256) void gemm_bias(const float* __restrict__ A,
                                                 const float* __restrict__ W,
                                                 const float* __restrict__ bias,
                                                 float* __restrict__ C,
                                                 int M, int N, int K) {
  __shared__ float Asf[16][68];
  __shared__ float Wsf[16][68];
  const int bm = blockIdx.y * 64;
  const int bn = blockIdx.x * 64;
  const int tid = threadIdx.x;
  const int tx = tid & 15, ty = tid >> 4;
  const int lr = tid >> 2;
  const int lk = (tid & 3) * 4;
  float acc[4][4] = {};

  for (int k0 = 0; k0 < K; k0 += 16) {
    {
      int m = bm + lr;
      float4 v = (m < M) ? *(const float4*)(A + (size_t)m * K + k0 + lk)
                         : make_float4(0.f, 0.f, 0.f, 0.f);
      Asf[lk + 0][lr] = v.x; Asf[lk + 1][lr] = v.y;
      Asf[lk + 2][lr] = v.z; Asf[lk + 3][lr] = v.w;
    }
    {
      int n = bn + lr;
      float4 v = (n < N) ? *(const float4*)(W + (size_t)n * K + k0 + lk)
                         : make_float4(0.f, 0.f, 0.f, 0.f);
      Wsf[lk + 0][lr] = v.x; Wsf[lk + 1][lr] = v.y;
      Wsf[lk + 2][lr] = v.z; Wsf[lk + 3][lr] = v.w;
    }
    __syncthreads();
#pragma unroll
    for (int kk = 0; kk < 16; ++kk) {
      float a[4], b[4];
#pragma unroll
      for (int i = 0; i < 4; ++i) a[i] = Asf[kk][ty * 4 + i];
#pragma unroll
      for (int j = 0; j < 4; ++j) b[j] = Wsf[kk][tx * 4 + j];
#pragma unroll
      for (int i = 0; i < 4; ++i)
#pragma unroll
        for (int j = 0; j < 4; ++j) acc[i][j] += a[i] * b[j];
    }
    __syncthreads();
  }

#pragma unroll
  for (int i = 0; i < 4; ++i) {
    int m = bm + ty * 4 + i;
    if (m >= M) continue;
#pragma unroll
    for (int j = 0; j < 4; ++j) {
      int n = bn + tx * 4 + j;
      if (n < N) C[(size_t)m * N + n] = acc[i][j] + (bias ? bias[n] : 0.f);
    }
  }
}

// ---------------------------------------------------------------- fused GATv2 aggregate
// One wave per destination node; logit + softmax + aggregate in registers.
// OBF: emit bf16 output (layer 1 -> feeds bf16 MFMA GEMMs of layer 2).
template <int D, bool DO_SILU, bool OBF>
__global__ __launch_bounds__(256) void k_gat_fused(
    const int* __restrict__ ssrc, const float* __restrict__ sattr,
    const int* __restrict__ rowoff, const int* __restrict__ boff,
    const int* __restrict__ cnti, const float* __restrict__ la,
    const float* __restrict__ xl, const float* __restrict__ xr,
    const float* __restrict__ We, const float* __restrict__ att,
    const float* __restrict__ bias, const float* __restrict__ w_ln,
    float* __restrict__ out, unsigned short* __restrict__ outb) {
  constexpr int VEC = D / 64;
  int n = blockIdx.x * 4 + (threadIdx.x >> 6);
  if (n >= NN) return;
  int lane = threadIdx.x & 63;
  int c0 = lane * VEC;

  float xd[VEC], we[VEC], at[VEC], acc[VEC] = {};
  float denom = 0.f;
#pragma unroll
  for (int k = 0; k < VEC; k++) {
    xd[k] = xr[(size_t)n * D + c0 + k];
    we[k] = We[c0 + k];
    at[k] = att[c0 + k];
  }

  int start = rowoff[n] + boff[n >> 8];
  int deg = cnti[n];
  for (int i = 0; i <= deg; i++) {          // last iteration = self-loop
    int s; float ea;
    if (i < deg) { s = ssrc[start + i]; ea = sattr[start + i]; }
    else         { s = n;               ea = la[n]; }
    const float* xsp = xl + (size_t)s * D + c0;
    float xs[VEC];
#pragma unroll
    for (int k = 0; k < VEC; k++) xs[k] = xsp[k];
    float part = 0.f;
#pragma unroll
    for (int k = 0; k < VEC; k++) {
      float v = xs[k] + xd[k] + ea * we[k];
      v = (v > 0.f) ? v : 0.2f * v;
      part += at[k] * v;
    }
#pragma unroll
    for (int o = 16; o > 0; o >>= 1) part += __shfl_xor(part, o);  // per-head
    float pe = __expf(part);
    denom += pe;
#pragma unroll
    for (int k = 0; k < VEC; k++) acc[k] += pe * xs[k];
  }

  float inv = 1.f / denom;
  float vv[VEC], ss = 0.f;
#pragma unroll
  for (int k = 0; k < VEC; k++) {
    float v = acc[k] * inv + bias[c0 + k];
    if (DO_SILU) v = v / (1.f + __expf(-v));
    vv[k] = v;
    ss += v * v;
  }
#pragma unroll
  for (int o = 32; o > 0; o >>= 1) ss += __shfl_xor(ss, o);        // full-wave
  float rinv = rsqrtf(ss / (float)D + 1e-5f);
#pragma unroll
  for (int k = 0; k < VEC; k++) {
    float o = vv[k] * rinv * w_ln[c0 + k];
    if (OBF) outb[(size_t)n * D + c0 + k] = f2b(o);
    else     out[(size_t)n * D + c0 + k] = o;
  }
}

// ---------------------------------------------------------------- launch
extern "C" void kernel_launch(void* const* d_in, const int* in_sizes, int n_in,
                              void* d_out, int out_size, void* d_ws, size_t ws_size,
                              hipStream_t stream) {
  const float* x     = (const float*)d_in[0];
  const int*   ei    = (const int*)  d_in[1];
  const float* eattr = (const float*)d_in[2];
  const float* Wl1   = (const float*)d_in[3];
  const float* bl1   = (const float*)d_in[4];
  const float* Wr1   = (const float*)d_in[5];
  const float* br1   = (const float*)d_in[6];
  const float* We1   = (const float*)d_in[7];
  const float* att1  = (const float*)d_in[8];
  const float* bias1 = (const float*)d_in[9];
  const float* Wl2   = (const float*)d_in[10];
  const float* bl2   = (const float*)d_in[11];
  const float* Wr2   = (const float*)d_in[12];
  const float* br2   = (const float*)d_in[13];
  const float* We2   = (const float*)d_in[14];
  const float* att2  = (const float*)d_in[15];
  const float* bias2 = (const float*)d_in[16];
  const float* w_ln1 = (const float*)d_in[17];
  const float* w_ln3 = (const float*)d_in[18];
  const float* W_out = (const float*)d_in[19];
  float* out = (float*)d_out;
  (void)in_sizes; (void)n_in; (void)out_size; (void)ws_size;

  const int* src = ei;
  const int* dst = ei + NE;

  char* wsp = (char*)d_ws;
  auto alloc = [&](size_t nbytes) {
    char* ptr = wsp;
    wsp += ((nbytes + 255) / 256) * 256;
    return ptr;
  };
  int*   cnti   = (int*)  alloc((size_t)NN * 4);     // }
  int*   cursor = (int*)  alloc((size_t)NN * 4);     // } zeroed together
  float* lsum   = (float*)alloc((size_t)NN * 4);     // }
  float* la     = (float*)alloc((size_t)NN * 4);
  int*   rowoff = (int*)  alloc((size_t)NN * 4);
  int*   bsum   = (int*)  alloc(128 * 4);
  int*   boff   = (int*)  alloc(128 * 4);
  int*   ssrc   = (int*)  alloc((size_t)NE * 4);
  float* sattr  = (float*)alloc((size_t)NE * 4);
  unsigned short* xb    = (unsigned short*)alloc((size_t)NN * D2 * 2);   // x bf16
  unsigned short* Wl1b  = (unsigned short*)alloc((size_t)D1 * D2 * 2);
  unsigned short* Wr1b  = (unsigned short*)alloc((size_t)D1 * D2 * 2);
  unsigned short* Wl2b  = (unsigned short*)alloc((size_t)D2 * D1 * 2);
  unsigned short* Wr2b  = (unsigned short*)alloc((size_t)D2 * D1 * 2);
  unsigned short* h1b   = (unsigned short*)alloc((size_t)NN * D1 * 2);
  float* xl1    = (float*)alloc((size_t)NN * D1 * 4);
  float* xr1    = (float*)alloc((size_t)NN * D1 * 4);
  float* xl2    = (float*)alloc((size_t)NN * D2 * 4);
  float* xr2    = (float*)alloc((size_t)NN * D2 * 4);
  float* h2     = (float*)alloc((size_t)NN * D2 * 4);

  // --- CSR build + self-loop attrs + bf16 casts ---
  k_zero<<<(3 * NN + 255) / 256, 256, 0, stream>>>(cnti, 3 * NN);
  k_f2b<<<((NN * D2 / 4) + 255) / 256, 256, 0, stream>>>(x, xb, NN * D2);
  k_f2b<<<((D1 * D2 / 4) + 255) / 256, 256, 0, stream>>>(Wl1, Wl1b, D1 * D2);
  k_f2b<<<((D1 * D2 / 4) + 255) / 256, 256, 0, stream>>>(Wr1, Wr1b, D1 * D2);
  k_f2b<<<((D1 * D2 / 4) + 255) / 256, 256, 0, stream>>>(Wl2, Wl2b, D2 * D1);
  k_f2b<<<((D1 * D2 / 4) + 255) / 256, 256, 0, stream>>>(Wr2, Wr2b, D2 * D1);
  k_deg<<<(NE + 255) / 256, 256, 0, stream>>>(dst, eattr, cnti, lsum);
  k_loopattr<<<(NN + 255) / 256, 256, 0, stream>>>(cnti, lsum, la);
  k_scan1<<<NB, 256, 0, stream>>>(cnti, rowoff, bsum);
  k_scan2<<<1, 128, 0, stream>>>(bsum, boff);
  k_fill<<<(NE + 255) / 256, 256, 0, stream>>>(src, dst, eattr, rowoff, boff,
                                               cursor, ssrc, sattr);

  const int GB = (NN + 3) / 4;
  const int MB = (NN + 127) / 128;   // 235 row-tiles

  // --- layer 1: xl1/xr1 = x @ W^T + b  (bf16 MFMA, fp32 out) ---
  gemm_mfma<128, 4><<<dim3(D1 / 128, MB), 256, 0, stream>>>(xb, Wl1b, bl1, xl1, NN, D1, D2);
  gemm_mfma<128, 4><<<dim3(D1 / 128, MB), 256, 0, stream>>>(xb, Wr1b, br1, xr1, NN, D1, D2);
  k_gat_fused<D1, true, true><<<GB, 256, 0, stream>>>(ssrc, sattr, rowoff, boff, cnti, la,
                                                      xl1, xr1, We1, att1, bias1, w_ln1,
                                                      nullptr, h1b);

  // --- layer 2 ---
  gemm_mfma<64, 2><<<dim3(D2 / 64, MB), 256, 0, stream>>>(h1b, Wl2b, bl2, xl2, NN, D2, D1);
  gemm_mfma<64, 2><<<dim3(D2 / 64, MB), 256, 0, stream>>>(h1b, Wr2b, br2, xr2, NN, D2, D1);
  k_gat_fused<D2, false, false><<<GB, 256, 0, stream>>>(ssrc, sattr, rowoff, boff, cnti, la,
                                                        xl2, xr2, We2, att2, bias2, w_ln3,
                                                        h2, nullptr);

  // --- classifier head (fp32) ---
  gemm_bias<<<dim3(1, (NN + 63) / 64), 256, 0, stream>>>(h2, W_out, nullptr, out, NN, NCLS, D2);
}

// Round 4
// 329.074 us; speedup vs baseline: 3.7485x; 1.2767x over previous
//
#include <hip/hip_runtime.h>
#include <cstddef>

#define NN   30000
#define NE   240000
#define D1   512
#define D2   128
#define NCLS 20
#define NB   ((NN + 255) / 256)   /* 118 scan blocks */

typedef __attribute__((ext_vector_type(8))) short short8;
typedef __attribute__((ext_vector_type(4))) float f32x4;
typedef __attribute__((ext_vector_type(8))) unsigned short u16x8;
typedef __attribute__((ext_vector_type(2))) unsigned short u16x2;

__device__ __forceinline__ unsigned short f2b(float f) {
  union { float f; unsigned int u; } c; c.f = f;
  unsigned int r = (c.u + 0x7fff + ((c.u >> 16) & 1)) >> 16;  // RNE
  return (unsigned short)r;
}
__device__ __forceinline__ float b2f(unsigned short u) {
  union { unsigned int u; float f; } c; c.u = (unsigned int)u << 16;
  return c.f;
}

// ---------------------------------------------------------------- utilities
__global__ __launch_bounds__(256) void k_zero(int* __restrict__ p, int n) {
  int i = blockIdx.x * 256 + threadIdx.x;
  if (i < n) p[i] = 0;
}

// one fused cast: x (960000 float4) + Wl1,Wr1 -> Wc1 + Wl2,Wr2 -> Wc2 (16384 float4 each)
__global__ __launch_bounds__(256) void k_cast_all(
    const float* __restrict__ x,
    const float* __restrict__ Wl1, const float* __restrict__ Wr1,
    const float* __restrict__ Wl2, const float* __restrict__ Wr2,
    unsigned short* __restrict__ xb,
    unsigned short* __restrict__ Wc1, unsigned short* __restrict__ Wc2) {
  int i = blockIdx.x * 256 + threadIdx.x;   // float4 index
  const float* in; unsigned short* outp; int off;
  if      (i <  960000) { in = x;   outp = xb;          off = i; }
  else if (i <  976384) { in = Wl1; outp = Wc1;         off = i -  960000; }
  else if (i <  992768) { in = Wr1; outp = Wc1 + 65536; off = i -  976384; }
  else if (i < 1009152) { in = Wl2; outp = Wc2;         off = i -  992768; }
  else if (i < 1025536) { in = Wr2; outp = Wc2 + 65536; off = i - 1009152; }
  else return;
  float4 v = ((const float4*)in)[off];
  ushort4 o;
  o.x = f2b(v.x); o.y = f2b(v.y); o.z = f2b(v.z); o.w = f2b(v.w);
  ((ushort4*)outp)[off] = o;
}

__global__ __launch_bounds__(256) void k_deg(const int* __restrict__ dst,
                                             const float* __restrict__ eattr,
                                             int* __restrict__ cnti,
                                             float* __restrict__ lsum) {
  int e = blockIdx.x * 256 + threadIdx.x;
  if (e < NE) {
    int d = dst[e];
    atomicAdd(&cnti[d], 1);
    atomicAdd(&lsum[d], eattr[e]);
  }
}

__global__ __launch_bounds__(256) void k_loopattr(const int* __restrict__ cnti,
                                                  const float* __restrict__ lsum,
                                                  float* __restrict__ la) {
  int n = blockIdx.x * 256 + threadIdx.x;
  if (n < NN) la[n] = lsum[n] / fmaxf((float)cnti[n], 1.0f);
}

__global__ __launch_bounds__(256) void k_scan1(const int* __restrict__ cnti,
                                               int* __restrict__ rowoff,
                                               int* __restrict__ bsum) {
  int i = blockIdx.x * 256 + threadIdx.x;
  int c = (i < NN) ? cnti[i] : 0;
  int lane = threadIdx.x & 63, w = threadIdx.x >> 6;
  int v = c;
#pragma unroll
  for (int o = 1; o < 64; o <<= 1) { int t = __shfl_up(v, o); if (lane >= o) v += t; }
  __shared__ int ws[4];
  if (lane == 63) ws[w] = v;
  __syncthreads();
  int add = 0;
  for (int k = 0; k < w; k++) add += ws[k];
  v += add;
  if (i < NN) rowoff[i] = v - c;
  if (threadIdx.x == 255) bsum[blockIdx.x] = v;
}

__global__ __launch_bounds__(128) void k_scan2(const int* __restrict__ bsum,
                                               int* __restrict__ boff) {
  __shared__ int s[128];
  int t = threadIdx.x;
  int orig = (t < NB) ? bsum[t] : 0;
  s[t] = orig;
  __syncthreads();
  for (int o = 1; o < 128; o <<= 1) {
    int v = (t >= o) ? s[t - o] : 0;
    __syncthreads();
    s[t] += v;
    __syncthreads();
  }
  boff[t] = s[t] - orig;
}

__global__ __launch_bounds__(256) void k_fill(const int* __restrict__ src,
                                              const int* __restrict__ dst,
                                              const float* __restrict__ eattr,
                                              const int* __restrict__ rowoff,
                                              const int* __restrict__ boff,
                                              int* __restrict__ cursor,
                                              int* __restrict__ ssrc,
                                              float* __restrict__ sattr) {
  int e = blockIdx.x * 256 + threadIdx.x;
  if (e < NE) {
    int d = dst[e];
    int pos = rowoff[d] + boff[d >> 8] + atomicAdd(&cursor[d], 1);
    ssrc[pos] = src[e];
    sattr[pos] = eattr[e];
  }
}

// ---------------------------------------------------------------- bf16 MFMA GEMM
// C[m,n] = sum_k A[m,k]*W[n,k] + bias[n], W = [Wl; Wr] concat in n.
// bias[n] = n < Nhalf ? bl[n] : br[n-Nhalf]. Output bf16 (row stride N).
// BM=128, BN=128, BK=32; 256 threads = 4 waves 2x2; 16x16x32 bf16 MFMA.
__global__ __launch_bounds__(256) void gemm_mfma(
    const unsigned short* __restrict__ A, const unsigned short* __restrict__ W,
    const float* __restrict__ bl, const float* __restrict__ br, int Nhalf,
    unsigned short* __restrict__ C, int M, int N, int K) {
  constexpr int BM = 128, BN = 128, BK = 32, LDK = BK + 8;
  __shared__ __align__(16) unsigned short As[BM * LDK];
  __shared__ __align__(16) unsigned short Bs[BN * LDK];
  const int bm = blockIdx.y * BM;
  const int bn = blockIdx.x * BN;
  const int tid = threadIdx.x;
  const int wid = tid >> 6, lane = tid & 63;
  const int wm = (wid >> 1) * 64;
  const int wn = (wid & 1) * 64;
  const int l16 = lane & 15, lq = lane >> 4;
  const int r0 = tid >> 2;
  const int ks = (tid & 3) * 8;

  f32x4 acc[4][4];
#pragma unroll
  for (int i = 0; i < 4; ++i)
#pragma unroll
    for (int j = 0; j < 4; ++j) acc[i][j] = (f32x4){0.f, 0.f, 0.f, 0.f};

  for (int k0 = 0; k0 < K; k0 += BK) {
#pragma unroll
    for (int p = 0; p < 2; ++p) {
      int r = r0 + p * 64;
      int gm = bm + r;
      uint4 v = {0u, 0u, 0u, 0u};
      if (gm < M) v = *(const uint4*)(A + (size_t)gm * K + k0 + ks);
      *(uint4*)&As[r * LDK + ks] = v;
      int gn = bn + r;
      uint4 w = {0u, 0u, 0u, 0u};
      if (gn < N) w = *(const uint4*)(W + (size_t)gn * K + k0 + ks);
      *(uint4*)&Bs[r * LDK + ks] = w;
    }
    __syncthreads();
    short8 af[4], bfr[4];
#pragma unroll
    for (int mt = 0; mt < 4; ++mt)
      af[mt] = *(const short8*)&As[(wm + mt * 16 + l16) * LDK + lq * 8];
#pragma unroll
    for (int nt = 0; nt < 4; ++nt)
      bfr[nt] = *(const short8*)&Bs[(wn + nt * 16 + l16) * LDK + lq * 8];
#pragma unroll
    for (int mt = 0; mt < 4; ++mt)
#pragma unroll
      for (int nt = 0; nt < 4; ++nt)
        acc[mt][nt] = __builtin_amdgcn_mfma_f32_16x16x32_bf16(
            af[mt], bfr[nt], acc[mt][nt], 0, 0, 0);
    __syncthreads();
  }

#pragma unroll
  for (int mt = 0; mt < 4; ++mt)
#pragma unroll
    for (int nt = 0; nt < 4; ++nt) {
      int col = bn + wn + nt * 16 + l16;
      float b = (col < Nhalf) ? bl[col] : br[col - Nhalf];
#pragma unroll
      for (int r = 0; r < 4; ++r) {
        int row = bm + wm + mt * 16 + lq * 4 + r;
        if (row < M) C[(size_t)row * N + col] = f2b(acc[mt][nt][r] + b);
      }
    }
}

// ---------------------------------------------------------------- fp32 GEMM (head only)
__global__ __launch_bounds__(256) void gemm_bias(const float* __restrict__ A,
                                                 const float* __restrict__ W,
                                                 float* __restrict__ C,
                                                 int M, int N, int K) {
  __shared__ float Asf[16][68];
  __shared__ float Wsf[16][68];
  const int bm = blockIdx.y * 64;
  const int bn = blockIdx.x * 64;
  const int tid = threadIdx.x;
  const int tx = tid & 15, ty = tid >> 4;
  const int lr = tid >> 2;
  const int lk = (tid & 3) * 4;
  float acc[4][4] = {};

  for (int k0 = 0; k0 < K; k0 += 16) {
    {
      int m = bm + lr;
      float4 v = (m < M) ? *(const float4*)(A + (size_t)m * K + k0 + lk)
                         : make_float4(0.f, 0.f, 0.f, 0.f);
      Asf[lk + 0][lr] = v.x; Asf[lk + 1][lr] = v.y;
      Asf[lk + 2][lr] = v.z; Asf[lk + 3][lr] = v.w;
    }
    {
      int n = bn + lr;
      float4 v = (n < N) ? *(const float4*)(W + (size_t)n * K + k0 + lk)
                         : make_float4(0.f, 0.f, 0.f, 0.f);
      Wsf[lk + 0][lr] = v.x; Wsf[lk + 1][lr] = v.y;
      Wsf[lk + 2][lr] = v.z; Wsf[lk + 3][lr] = v.w;
    }
    __syncthreads();
#pragma unroll
    for (int kk = 0; kk < 16; ++kk) {
      float a[4], b[4];
#pragma unroll
      for (int i = 0; i < 4; ++i) a[i] = Asf[kk][ty * 4 + i];
#pragma unroll
      for (int j = 0; j < 4; ++j) b[j] = Wsf[kk][tx * 4 + j];
#pragma unroll
      for (int i = 0; i < 4; ++i)
#pragma unroll
        for (int j = 0; j < 4; ++j) acc[i][j] += a[i] * b[j];
    }
    __syncthreads();
  }

#pragma unroll
  for (int i = 0; i < 4; ++i) {
    int m = bm + ty * 4 + i;
    if (m >= M) continue;
#pragma unroll
    for (int j = 0; j < 4; ++j) {
      int n = bn + tx * 4 + j;
      if (n < N) C[(size_t)m * N + n] = acc[i][j];
    }
  }
}

// ---------------------------------------------------------------- fused GATv2 aggregate
// One wave per destination node. xlr: bf16, row stride 2*D, layout [xl | xr].
// 2x-unrolled edge loop: two gathers + two reduce chains in flight.
template <int D, bool DO_SILU, bool OBF>
__global__ __launch_bounds__(256) void k_gat_fused(
    const int* __restrict__ ssrc, const float* __restrict__ sattr,
    const int* __restrict__ rowoff, const int* __restrict__ boff,
    const int* __restrict__ cnti, const float* __restrict__ la,
    const unsigned short* __restrict__ xlr,
    const float* __restrict__ We, const float* __restrict__ att,
    const float* __restrict__ bias, const float* __restrict__ w_ln,
    float* __restrict__ out, unsigned short* __restrict__ outb) {
  constexpr int VEC = D / 64;
  constexpr int STR = 2 * D;
  typedef __attribute__((ext_vector_type(VEC))) unsigned short uvec;
  int n = blockIdx.x * 4 + (threadIdx.x >> 6);
  if (n >= NN) return;
  int lane = threadIdx.x & 63;
  int c0 = lane * VEC;

  float xd[VEC], we[VEC], at[VEC], acc[VEC] = {};
  float denom = 0.f;
  {
    uvec u = *(const uvec*)(xlr + (size_t)n * STR + D + c0);   // xr row
#pragma unroll
    for (int k = 0; k < VEC; k++) {
      xd[k] = b2f(u[k]);
      we[k] = We[c0 + k];
      at[k] = att[c0 + k];
    }
  }

  int start = rowoff[n] + boff[n >> 8];
  int deg = cnti[n];
  float lan = la[n];
  int i = 0;
  for (; i + 2 <= deg; i += 2) {
    int s0 = ssrc[start + i], s1 = ssrc[start + i + 1];
    float ea0 = sattr[start + i], ea1 = sattr[start + i + 1];
    uvec u0 = *(const uvec*)(xlr + (size_t)s0 * STR + c0);
    uvec u1 = *(const uvec*)(xlr + (size_t)s1 * STR + c0);
    float xs0[VEC], xs1[VEC];
#pragma unroll
    for (int k = 0; k < VEC; k++) { xs0[k] = b2f(u0[k]); xs1[k] = b2f(u1[k]); }
    float p0 = 0.f, p1 = 0.f;
#pragma unroll
    for (int k = 0; k < VEC; k++) {
      float v0 = xs0[k] + xd[k] + ea0 * we[k];
      float v1 = xs1[k] + xd[k] + ea1 * we[k];
      v0 = (v0 > 0.f) ? v0 : 0.2f * v0;
      v1 = (v1 > 0.f) ? v1 : 0.2f * v1;
      p0 += at[k] * v0;
      p1 += at[k] * v1;
    }
#pragma unroll
    for (int o = 16; o > 0; o >>= 1) {      // per-head (half-wave), 2 chains
      p0 += __shfl_xor(p0, o);
      p1 += __shfl_xor(p1, o);
    }
    float pe0 = __expf(p0), pe1 = __expf(p1);
    denom += pe0 + pe1;
#pragma unroll
    for (int k = 0; k < VEC; k++) acc[k] += pe0 * xs0[k] + pe1 * xs1[k];
  }
  for (; i <= deg; ++i) {                   // tail edge (0/1) + self-loop
    int s; float ea;
    if (i < deg) { s = ssrc[start + i]; ea = sattr[start + i]; }
    else         { s = n;               ea = lan; }
    uvec u = *(const uvec*)(xlr + (size_t)s * STR + c0);
    float xs[VEC];
#pragma unroll
    for (int k = 0; k < VEC; k++) xs[k] = b2f(u[k]);
    float part = 0.f;
#pragma unroll
    for (int k = 0; k < VEC; k++) {
      float v = xs[k] + xd[k] + ea * we[k];
      v = (v > 0.f) ? v : 0.2f * v;
      part += at[k] * v;
    }
#pragma unroll
    for (int o = 16; o > 0; o >>= 1) part += __shfl_xor(part, o);
    float pe = __expf(part);
    denom += pe;
#pragma unroll
    for (int k = 0; k < VEC; k++) acc[k] += pe * xs[k];
  }

  float inv = 1.f / denom;
  float vv[VEC], ss = 0.f;
#pragma unroll
  for (int k = 0; k < VEC; k++) {
    float v = acc[k] * inv + bias[c0 + k];
    if (DO_SILU) v = v / (1.f + __expf(-v));
    vv[k] = v;
    ss += v * v;
  }
#pragma unroll
  for (int o = 32; o > 0; o >>= 1) ss += __shfl_xor(ss, o);        // full-wave
  float rinv = rsqrtf(ss / (float)D + 1e-5f);
#pragma unroll
  for (int k = 0; k < VEC; k++) {
    float o = vv[k] * rinv * w_ln[c0 + k];
    if (OBF) outb[(size_t)n * D + c0 + k] = f2b(o);
    else     out[(size_t)n * D + c0 + k] = o;
  }
}

// ---------------------------------------------------------------- launch
extern "C" void kernel_launch(void* const* d_in, const int* in_sizes, int n_in,
                              void* d_out, int out_size, void* d_ws, size_t ws_size,
                              hipStream_t stream) {
  const float* x     = (const float*)d_in[0];
  const int*   ei    = (const int*)  d_in[1];
  const float* eattr = (const float*)d_in[2];
  const float* Wl1   = (const float*)d_in[3];
  const float* bl1   = (const float*)d_in[4];
  const float* Wr1   = (const float*)d_in[5];
  const float* br1   = (const float*)d_in[6];
  const float* We1   = (const float*)d_in[7];
  const float* att1  = (const float*)d_in[8];
  const float* bias1 = (const float*)d_in[9];
  const float* Wl2   = (const float*)d_in[10];
  const float* bl2   = (const float*)d_in[11];
  const float* Wr2   = (const float*)d_in[12];
  const float* br2   = (const float*)d_in[13];
  const float* We2   = (const float*)d_in[14];
  const float* att2  = (const float*)d_in[15];
  const float* bias2 = (const float*)d_in[16];
  const float* w_ln1 = (const float*)d_in[17];
  const float* w_ln3 = (const float*)d_in[18];
  const float* W_out = (const float*)d_in[19];
  float* out = (float*)d_out;
  (void)in_sizes; (void)n_in; (void)out_size; (void)ws_size;

  const int* src = ei;
  const int* dst = ei + NE;

  char* wsp = (char*)d_ws;
  auto alloc = [&](size_t nbytes) {
    char* ptr = wsp;
    wsp += ((nbytes + 255) / 256) * 256;
    return ptr;
  };
  int*   cnti   = (int*)  alloc((size_t)NN * 4);     // }
  int*   cursor = (int*)  alloc((size_t)NN * 4);     // } zeroed together
  float* lsum   = (float*)alloc((size_t)NN * 4);     // }
  float* la     = (float*)alloc((size_t)NN * 4);
  int*   rowoff = (int*)  alloc((size_t)NN * 4);
  int*   bsum   = (int*)  alloc(128 * 4);
  int*   boff   = (int*)  alloc(128 * 4);
  int*   ssrc   = (int*)  alloc((size_t)NE * 4);
  float* sattr  = (float*)alloc((size_t)NE * 4);
  unsigned short* xb   = (unsigned short*)alloc((size_t)NN * D2 * 2);
  unsigned short* Wc1  = (unsigned short*)alloc((size_t)2 * D1 * D2 * 2);
  unsigned short* Wc2  = (unsigned short*)alloc((size_t)2 * D2 * D1 * 2);
  unsigned short* xlr1 = (unsigned short*)alloc((size_t)NN * 2 * D1 * 2);  // [xl1|xr1]
  unsigned short* h1b  = (unsigned short*)alloc((size_t)NN * D1 * 2);
  unsigned short* xlr2 = (unsigned short*)alloc((size_t)NN * 2 * D2 * 2);  // [xl2|xr2]
  float* h2     = (float*)alloc((size_t)NN * D2 * 4);

  // --- CSR build + self-loop attrs + single fused cast ---
  k_zero<<<(3 * NN + 255) / 256, 256, 0, stream>>>(cnti, 3 * NN);
  k_cast_all<<<(1025536 + 255) / 256, 256, 0, stream>>>(x, Wl1, Wr1, Wl2, Wr2, xb, Wc1, Wc2);
  k_deg<<<(NE + 255) / 256, 256, 0, stream>>>(dst, eattr, cnti, lsum);
  k_loopattr<<<(NN + 255) / 256, 256, 0, stream>>>(cnti, lsum, la);
  k_scan1<<<NB, 256, 0, stream>>>(cnti, rowoff, bsum);
  k_scan2<<<1, 128, 0, stream>>>(bsum, boff);
  k_fill<<<(NE + 255) / 256, 256, 0, stream>>>(src, dst, eattr, rowoff, boff,
                                               cursor, ssrc, sattr);

  const int GB = (NN + 3) / 4;
  const int MB = (NN + 127) / 128;   // 235 row-tiles

  // --- layer 1: xlr1 = x @ [Wl1;Wr1]^T + [bl1;br1]  (bf16 out, N=1024) ---
  gemm_mfma<<<dim3(2 * D1 / 128, MB), 256, 0, stream>>>(xb, Wc1, bl1, br1, D1,
                                                        xlr1, NN, 2 * D1, D2);
  k_gat_fused<D1, true, true><<<GB, 256, 0, stream>>>(ssrc, sattr, rowoff, boff, cnti, la,
                                                      xlr1, We1, att1, bias1, w_ln1,
                                                      nullptr, h1b);

  // --- layer 2: xlr2 = h1 @ [Wl2;Wr2]^T + [bl2;br2]  (bf16 out, N=256) ---
  gemm_mfma<<<dim3(2 * D2 / 128, MB), 256, 0, stream>>>(h1b, Wc2, bl2, br2, D2,
                                                        xlr2, NN, 2 * D2, D1);
  k_gat_fused<D2, false, false><<<GB, 256, 0, stream>>>(ssrc, sattr, rowoff, boff, cnti, la,
                                                        xlr2, We2, att2, bias2, w_ln3,
                                                        h2, nullptr);

  // --- classifier head (fp32) ---
  gemm_bias<<<dim3(1, (NN + 63) / 64), 256, 0, stream>>>(h2, W_out, out, NN, NCLS, D2);
}